// Round 9
// baseline (482.446 us; speedup 1.0000x reference)
//
#include <hip/hip_runtime.h>
#include <math.h>

#define BB 8
#define FF 256
#define SS 1024
#define KK 16
#define ITERS 5

typedef unsigned long long ull;

// R12: coop grid.sync = 94us/barrier on MI355X -> multi-launch only.
// R10: 64x64/wave = 1 wave/SIMD, dist 147us (occupancy collapse).
// R5 (measured R8): 64x64/block 2-wave = 124us, VALUBusy 50%, occ 17%.
//   -> half the time is still vmcnt/barrier exposure (depth-1 prefetch,
//   2 barriers per 1024-cyc chunk). R8: depth-2 prefetch, pair-chunks.

// ---------- wm stage 1: partial column sums of w ----------
#define ICH 8
__global__ void wm_part_kernel(const float* __restrict__ w, float* __restrict__ part) {
    int j = blockIdx.x * 256 + threadIdx.x;
    int ic = blockIdx.y, b = blockIdx.z;
    const float* wp = w + (size_t)b * SS * SS + (size_t)ic * (SS / ICH) * SS + j;
    float s = 0.f;
#pragma unroll 16
    for (int i = 0; i < SS / ICH; ++i) s += wp[(size_t)i * SS];
    part[((size_t)ic * BB + b) * SS + j] = s;
}

// ---------- d[b][i][j] = sum_f |x[b][f][i] - x[b][f][j]| ----------
// R8: 64x64 tile per block, 2 waves (32x64 rows, 4x8 acc/lane), SIX
// 1024-float LDS buffers (24 KB), chunks processed in PAIRS:
//   bar#1 (pair p-2 retired) -> stage p+4,p+5 (into bufs (p-2)%6,(p-1)%6)
//   -> vmcnt(8) (chunks p,p+1 landed; p+2..p+5 in flight) -> bar#2 ->
//   compute p, p+1.
// Loads wait ~2 pair-iters (>=4096 VALU cyc) -> latency hidden at any
// occupancy; 32 barriers (was 64). f-order per element unchanged -> d
// bitwise identical to R3-verified output.
#define FCD 8
#define TS 64
#define NT (SS / TS)
__device__ __forceinline__ void async_copy16(const float* g, const float* s) {
    __builtin_amdgcn_global_load_lds((const __attribute__((address_space(1))) void*)g,
                                     (__attribute__((address_space(3))) void*)s, 16, 0, 0);
}

__global__ __launch_bounds__(128, 4) void dist_kernel(const float* __restrict__ x,
                                                      float* __restrict__ d) {
    __shared__ float smem[6 * 1024];   // buf c%6: [A 512 | B 512]
    int tid = threadIdx.x;
    int wave = tid >> 6, lane = tid & 63;
    int b = blockIdx.y;
    int w = blockIdx.x;                 // 0..135 triangular tile id (64x64 tiles)
    int it = 0, rem = w;
    while (rem >= NT - it) { rem -= NT - it; ++it; }
    int jt = it + rem;
    int i0 = it * TS, j0 = jt * TS;
    const float* xb = x + (size_t)b * FF * SS;
    float* db = d + (size_t)b * SS * SS;
    int rl = wave * 32 + (lane >> 3) * 4;   // compute rows (4)
    int cl = (lane & 7) * 8;                // compute cols (8)
    int sF = tid >> 4, sT = (tid & 15) * 4; // staging: f=tid>>4, tok=(tid&15)*4

    float acc[4][8] = {};

    auto stage = [&](int c) {
        // wave-uniform LDS base (wave covers f rows 4w..4w+3 of the chunk)
        float* A = smem + (c % 6) * 1024 + wave * 256;
        const float* base = xb + ((size_t)c * FCD + sF) * SS + sT;
        async_copy16(base + i0, A);          // A: 8f x 64tok
        async_copy16(base + j0, A + 512);    // B
    };
    auto compute = [&](int c) {
        const float* A = smem + (c % 6) * 1024;
        const float* B = A + 512;
#pragma unroll
        for (int f = 0; f < FCD; ++f) {
            float4 a4 = *(const float4*)(A + f * 64 + rl);
            float4 b0 = *(const float4*)(B + f * 64 + cl);
            float4 b1 = *(const float4*)(B + f * 64 + cl + 4);
            float av[4] = {a4.x, a4.y, a4.z, a4.w};
            float bv[8] = {b0.x, b0.y, b0.z, b0.w, b1.x, b1.y, b1.z, b1.w};
#pragma unroll
            for (int r = 0; r < 4; ++r)
#pragma unroll
                for (int c2 = 0; c2 < 8; ++c2)
                    acc[r][c2] += fabsf(av[r] - bv[c2]);
        }
    };

    stage(0); stage(1); stage(2); stage(3);   // 8 loads in flight
#pragma unroll 1
    for (int p = 0; p < FF / FCD; p += 2) {
        // bar#1: all waves retired pair p-2 -> bufs (p-2)%6,(p-1)%6 free
        asm volatile("s_barrier" ::: "memory");
        if (p < 28) {
            stage(p + 4); stage(p + 5);
            // in flight: chunks p+2..p+5 = 8 loads; chunks p,p+1 landed
            asm volatile("s_waitcnt vmcnt(8)" ::: "memory");
        } else if (p == 28) {
            asm volatile("s_waitcnt vmcnt(4)" ::: "memory");
        } else {
            asm volatile("s_waitcnt vmcnt(0)" ::: "memory");
        }
        // bar#2: ALL waves' chunk-p,p+1 loads visible
        asm volatile("s_barrier" ::: "memory");
        compute(p); compute(p + 1);
    }

    // direct tile: rows i0+rl+r, cols j0+cl..cl+7
#pragma unroll
    for (int r = 0; r < 4; ++r) {
        float4 v0 = make_float4(acc[r][0], acc[r][1], acc[r][2], acc[r][3]);
        float4 v1 = make_float4(acc[r][4], acc[r][5], acc[r][6], acc[r][7]);
        float* row = &db[(size_t)(i0 + rl + r) * SS + j0 + cl];
        *(float4*)row = v0;
        *(float4*)(row + 4) = v1;
    }
    if (it != jt) {
        // mirror straight from registers (d bitwise symmetric)
#pragma unroll
        for (int c = 0; c < 8; ++c) {
            float4 v = make_float4(acc[0][c], acc[1][c], acc[2][c], acc[3][c]);
            *(float4*)&db[(size_t)(j0 + cl + c) * SS + i0 + rl] = v;
        }
    }
}

// ---------- wm finalize + topk (jax.lax.top_k) + initial assign, fused ----------
// wm > 0 strictly (means of uniform[0,1)), so float bits are order-monotonic.
__global__ __launch_bounds__(1024) void topk_assign_kernel(const float* __restrict__ part,
                                                           float* __restrict__ wm,
                                                           const float* __restrict__ d,
                                                           int* __restrict__ assign) {
    int b = blockIdx.x;
    int tid = threadIdx.x;          // == token index
    int lane = tid & 63, wv = tid >> 6;
    __shared__ ull red[16];
    __shared__ int ctr_s[KK];
    float v = 0.f;
#pragma unroll
    for (int ic = 0; ic < ICH; ++ic) v += part[((size_t)ic * BB + b) * SS + tid];
    v *= (1.0f / SS);
    wm[b * SS + tid] = v;
    ull key = (((ull)__float_as_uint(v)) << 32) | (ull)(0xFFFFFFFFu - (unsigned)tid);
    for (int k = 0; k < KK; ++k) {
        ull kk = key;
#pragma unroll
        for (int off = 32; off; off >>= 1) {
            ull o = __shfl_down(kk, off, 64);
            if (o > kk) kk = o;
        }
        if (lane == 0) red[wv] = kk;
        __syncthreads();
        if (wv == 0) {
            ull k2 = (lane < 16) ? red[lane] : 0ull;
#pragma unroll
            for (int off = 8; off; off >>= 1) {
                ull o = __shfl_down(k2, off, 64);
                if (o > k2) k2 = o;
            }
            if (lane == 0) red[0] = k2;
        }
        __syncthreads();
        ull W = red[0];
        int widx = (int)(0xFFFFFFFFu - (unsigned)(W & 0xFFFFFFFFu));
        if (tid == widx) key = 0;
        if (tid == 0) ctr_s[k] = widx;
        __syncthreads();
    }
    const float* db = d + (size_t)b * SS * SS;
    float bv = INFINITY;
    int bk = 0;
#pragma unroll
    for (int k = 0; k < KK; ++k) {
        float vv = db[(size_t)ctr_s[k] * SS + tid];
        if (vv < bv) { bv = vv; bk = k; }
    }
    assign[b * SS + tid] = bk;
}

// ---------- R8: cost + medoid update FUSED via last-block-per-batch ----------
// cost body verbatim (bitwise-identical cost[]). Then threadfence +
// atomicAdd(counter[b]); the 64th block acquire-fences and computes the
// medoid argmin + new assign (or final gather) for the whole batch.
// All replaced reductions are packed-key mins over DISTINCT keys ->
// unique minimum -> reduction-topology-independent -> identical results.
// Kills 5 launches and the 4x-redundant medoid recompute.
#define RPB 16
__global__ __launch_bounds__(256) void cost_update_kernel(
        const float* __restrict__ d, const float* __restrict__ wm,
        int* __restrict__ assign, float* __restrict__ cost,
        const float* __restrict__ x, float* __restrict__ out,
        int* __restrict__ counter, int last) {
    int b = blockIdx.y;
    int ib = blockIdx.x;
    int tid = threadIdx.x;
    int lane = tid & 63, wv = tid >> 6;
    __shared__ float wmv[SS];
    __shared__ int asg[SS];
    __shared__ float cost_s[SS];
    __shared__ int ctr_s[KK];
    __shared__ int lastflag;
    *(float4*)&wmv[tid * 4] = *(const float4*)&wm[b * SS + tid * 4];
    *(int4*)&asg[tid * 4] = *(const int4*)&assign[b * SS + tid * 4];
    __syncthreads();
    const float* db = d + (size_t)b * SS * SS;
    // ---- cost rows ib*16 + wv*4 + r (verbatim cost_kernel body) ----
#pragma unroll
    for (int r = 0; r < RPB / 4; ++r) {
        int i = ib * RPB + wv * (RPB / 4) + r;
        int my = asg[i];
        const float* drow = db + (size_t)i * SS;
        float s = 0.f;
#pragma unroll
        for (int c = 0; c < SS / 256; ++c) {      // 4 sweeps of 64 lanes x float4
            int j = c * 256 + lane * 4;
            float4 dv = *(const float4*)&drow[j];
            float4 wv4 = *(const float4*)&wmv[j];
            int4 a4 = *(const int4*)&asg[j];
            s += (a4.x == my) ? dv.x * wv4.x : 0.f;
            s += (a4.y == my) ? dv.y * wv4.y : 0.f;
            s += (a4.z == my) ? dv.z * wv4.z : 0.f;
            s += (a4.w == my) ? dv.w * wv4.w : 0.f;
        }
#pragma unroll
        for (int off = 32; off; off >>= 1) s += __shfl_down(s, off, 64);
        if (lane == 0) cost[b * SS + i] = s;
    }
    // ---- release our cost writes, elect the last block of this batch ----
    __threadfence();
    if (tid == 0) lastflag = (atomicAdd(&counter[b], 1) == (int)gridDim.x - 1);
    __syncthreads();
    if (!lastflag) return;
    __threadfence();   // acquire: all 64 blocks' cost writes now visible
    *(float4*)&cost_s[tid * 4] = *(const float4*)&cost[b * SS + tid * 4];
    __syncthreads();
    // ---- medoid argmin: 4 waves x 4 clusters, same per-cluster scan ----
#pragma unroll
    for (int q = 0; q < 4; ++q) {
        int k = wv + q * 4;
        ull best = ~0ull;
        for (int c = 0; c < SS / 64; ++c) {
            int i = c * 64 + lane;
            if (asg[i] == k) {
                ull key = (((ull)__float_as_uint(cost_s[i])) << 32) | (unsigned)i;
                if (key < best) best = key;
            }
        }
#pragma unroll
        for (int off = 32; off; off >>= 1) {
            ull o = __shfl_down(best, off, 64);
            if (o < best) best = o;
        }
        if (lane == 0) ctr_s[k] = (best == ~0ull) ? 0 : (int)(best & 0xFFFFFFFFu);
    }
    __syncthreads();
    if (!last) {
        // new assign, whole batch: 4 tokens/thread, k ascending, packed-key
        // min (distinct k -> unique min, == old hierarchical reduction)
#pragma unroll
        for (int q = 0; q < 4; ++q) {
            int tok = q * 256 + tid;
            ull bk = ~0ull;
#pragma unroll
            for (int k = 0; k < KK; ++k) {
                float vv = db[(size_t)ctr_s[k] * SS + tok];
                ull key = (((ull)__float_as_uint(vv)) << 32) | (unsigned)k;
                if (key < bk) bk = key;
            }
            assign[b * SS + tok] = (int)(bk & 0xFFFFFFFFu);
        }
    } else {
        // final gather: out[b][f][k] = x[b][f][ctr[k]]
        for (int e = tid; e < FF * KK; e += 256) {
            int f = e / KK, k2 = e % KK;
            out[((size_t)b * FF + f) * KK + k2] = x[((size_t)b * FF + f) * SS + ctr_s[k2]];
        }
    }
}

extern "C" void kernel_launch(void* const* d_in, const int* in_sizes, int n_in,
                              void* d_out, int out_size, void* d_ws, size_t ws_size,
                              hipStream_t stream) {
    const float* x = (const float*)d_in[0];   // [B,F,S]
    const float* w = (const float*)d_in[1];   // [B,S,S]
    float* out = (float*)d_out;               // [B,F,K]

    char* ws = (char*)d_ws;
    float* d = (float*)ws;                              // B*S*S floats = 33.55 MB
    size_t off = (size_t)BB * SS * SS * sizeof(float);
    float* wm = (float*)(ws + off);   off += (size_t)BB * SS * sizeof(float);
    int* assign = (int*)(ws + off);   off += (size_t)BB * SS * sizeof(int);
    float* cost = (float*)(ws + off); off += (size_t)BB * SS * sizeof(float);
    float* part = (float*)(ws + off); // [ICH][B][S] = 256 KB
    // counters alias part: part is dead after topk consumes it; the memset
    // below is stream-ordered after topk. ITERS*BB ints = 160 B.
    int* counters = (int*)part;

    // dist first, wm_part second — independent; wm_part backfills the tail.
    dist_kernel<<<dim3(136, BB), 128, 0, stream>>>(x, d);
    wm_part_kernel<<<dim3(SS / 256, ICH, BB), 256, 0, stream>>>(w, part);
    topk_assign_kernel<<<BB, 1024, 0, stream>>>(part, wm, d, assign);
    hipMemsetAsync(counters, 0, ITERS * BB * sizeof(int), stream);
    for (int itr = 0; itr < ITERS; ++itr) {
        cost_update_kernel<<<dim3(SS / RPB, BB), 256, 0, stream>>>(
            d, wm, assign, cost, x, out, counters + itr * BB,
            itr == ITERS - 1 ? 1 : 0);
    }
}

// Round 13
// 228.159 us; speedup vs baseline: 2.1145x; 2.1145x over previous
//
#include <hip/hip_runtime.h>
#include <math.h>

#define BB 8
#define FF 256
#define SS 1024
#define KK 16
#define ITERS 5

typedef unsigned long long ull;

// SESSION LEDGER (measured):
// R12 coop grid.sync: 94us/barrier -> multi-launch only.
// R10 64x64/wave: occupancy collapse, dist 147us.
// R5  64x64/block 2-wave barriers: dist 124us, VALUBusy 52%.
// R8  pair-chunks depth-2 + barriers: dist 119.6us (barriers couple waves
//     in lockstep -> stalls coincide; both pipes <30% utilized).
// R8  cost+update last-block fusion: ~70us/iter (update phase shrank
//     4096->256 threads/batch + full-grid drain tail). REVERTED.
// Best dist structure: R9 32x32 WAVE-PRIVATE, zero barriers, 4.1
// waves/SIMD (95us prev session). This round: R9 + depth-2 prefetch.

// ---------- wm stage 1: partial column sums of w ----------
#define ICH 8
__global__ void wm_part_kernel(const float* __restrict__ w, float* __restrict__ part) {
    int j = blockIdx.x * 256 + threadIdx.x;
    int ic = blockIdx.y, b = blockIdx.z;
    const float* wp = w + (size_t)b * SS * SS + (size_t)ic * (SS / ICH) * SS + j;
    float s = 0.f;
#pragma unroll 16
    for (int i = 0; i < SS / ICH; ++i) s += wp[(size_t)i * SS];
    part[((size_t)ic * BB + b) * SS + j] = s;
}

// ---------- d[b][i][j] = sum_f |x[b][f][i] - x[b][f][j]| ----------
// R10: R9's 32x32 wave-private tiles (2 waves/block, no barriers, 4224
// waves = 4.1/SIMD) + FOUR private LDS buffers (depth-2 prefetch,
// vmcnt(4)): chunk c's loads issued 2 chunks (~1000+cyc) earlier -> L2
// latency fully hidden (R9's depth-1 vmcnt(2) exposed ~200cyc/chunk).
// 16 KB/block -> LDS allows 10 blocks/CU, grid-limited at 8.25.
// f ascending per element -> d bitwise identical to all passing runs.
#define FCD 8
#define TS 32
#define NT (SS / TS)
__device__ __forceinline__ void async_copy16(const float* g, const float* s) {
    __builtin_amdgcn_global_load_lds((const __attribute__((address_space(1))) void*)g,
                                     (__attribute__((address_space(3))) void*)s, 16, 0, 0);
}

__global__ __launch_bounds__(128, 4) void dist_kernel(const float* __restrict__ x,
                                                      float* __restrict__ d) {
    __shared__ float smem[4096];   // per wave (2048): 4 bufs x [A 256 | B 256]
    int tid = threadIdx.x;
    int wave = tid >> 6, lane = tid & 63;
    int b = blockIdx.y;
    int w = blockIdx.x * 2 + wave;      // 0..527 triangular tile id (32x32 tiles)
    int it = 0, rem = w;
    while (rem >= NT - it) { rem -= NT - it; ++it; }
    int jt = it + rem;
    int i0 = it * TS, j0 = jt * TS;
    const float* xb = x + (size_t)b * FF * SS;
    float* db = d + (size_t)b * SS * SS;
    float* wbase = smem + wave * 2048;
    int ly = lane >> 3, lx = lane & 7;           // 8x8 lane grid, 4x4 each
    int sFl = lane >> 3, sTk = (lane & 7) * 4;   // staging: 8 f-rows x 32 tok/inst

    float acc[4][4] = {};

    auto stage = [&](int c) {
        float* A = wbase + (c & 3) * 512;
        const float* base = xb + ((size_t)c * FCD + sFl) * SS;
        async_copy16(base + i0 + sTk, A);          // A chunk: 8f x 32tok = 1 inst
        async_copy16(base + j0 + sTk, A + 256);    // B chunk
    };
    auto compute = [&](int c) {
        const float* A = wbase + (c & 3) * 512;
        const float* B = A + 256;
#pragma unroll
        for (int f = 0; f < FCD; ++f) {
            float4 a = *(const float4*)(A + f * 32 + ly * 4);
            float4 bb = *(const float4*)(B + f * 32 + lx * 4);
            float av[4] = {a.x, a.y, a.z, a.w};
            float bv[4] = {bb.x, bb.y, bb.z, bb.w};
#pragma unroll
            for (int r = 0; r < 4; ++r)
#pragma unroll
                for (int cc = 0; cc < 4; ++cc)
                    acc[r][cc] += fabsf(av[r] - bv[cc]);
        }
    };

    stage(0); stage(1);                 // 4 loads in flight (depth-2)
#pragma unroll 1
    for (int c = 0; c < FF / FCD - 2; ++c) {
        // WAR: buf (c+2)&3 == (c-2)&3; compute(c-2)'s ds_reads retired
        asm volatile("s_waitcnt lgkmcnt(0)" ::: "memory");
        stage(c + 2);
        // in flight: chunks c+1,c+2 (4 loads); chunk c's 2 have landed
        asm volatile("s_waitcnt vmcnt(4)" ::: "memory");
        compute(c);
    }
    asm volatile("s_waitcnt vmcnt(2)" ::: "memory");
    compute(30);
    asm volatile("s_waitcnt vmcnt(0)" ::: "memory");
    compute(31);

    // direct tile: rows i0+ly*4+r, cols j0+lx*4
#pragma unroll
    for (int r = 0; r < 4; ++r) {
        float4 v = make_float4(acc[r][0], acc[r][1], acc[r][2], acc[r][3]);
        *(float4*)&db[(size_t)(i0 + ly * 4 + r) * SS + j0 + lx * 4] = v;
    }
    if (it != jt) {
        // mirror straight from registers (d bitwise symmetric)
#pragma unroll
        for (int c = 0; c < 4; ++c) {
            float4 v = make_float4(acc[0][c], acc[1][c], acc[2][c], acc[3][c]);
            *(float4*)&db[(size_t)(j0 + lx * 4 + c) * SS + i0 + ly * 4] = v;
        }
    }
}

// ---------- wm finalize + topk (jax.lax.top_k) + initial assign, fused ----------
// wm > 0 strictly (means of uniform[0,1)), so float bits are order-monotonic.
__global__ __launch_bounds__(1024) void topk_assign_kernel(const float* __restrict__ part,
                                                           float* __restrict__ wm,
                                                           const float* __restrict__ d,
                                                           int* __restrict__ assign) {
    int b = blockIdx.x;
    int tid = threadIdx.x;          // == token index
    int lane = tid & 63, wv = tid >> 6;
    __shared__ ull red[16];
    __shared__ int ctr_s[KK];
    float v = 0.f;
#pragma unroll
    for (int ic = 0; ic < ICH; ++ic) v += part[((size_t)ic * BB + b) * SS + tid];
    v *= (1.0f / SS);
    wm[b * SS + tid] = v;
    ull key = (((ull)__float_as_uint(v)) << 32) | (ull)(0xFFFFFFFFu - (unsigned)tid);
    for (int k = 0; k < KK; ++k) {
        ull kk = key;
#pragma unroll
        for (int off = 32; off; off >>= 1) {
            ull o = __shfl_down(kk, off, 64);
            if (o > kk) kk = o;
        }
        if (lane == 0) red[wv] = kk;
        __syncthreads();
        if (wv == 0) {
            ull k2 = (lane < 16) ? red[lane] : 0ull;
#pragma unroll
            for (int off = 8; off; off >>= 1) {
                ull o = __shfl_down(k2, off, 64);
                if (o > k2) k2 = o;
            }
            if (lane == 0) red[0] = k2;
        }
        __syncthreads();
        ull W = red[0];
        int widx = (int)(0xFFFFFFFFu - (unsigned)(W & 0xFFFFFFFFu));
        if (tid == widx) key = 0;
        if (tid == 0) ctr_s[k] = widx;
        __syncthreads();
    }
    const float* db = d + (size_t)b * SS * SS;
    float bv = INFINITY;
    int bk = 0;
#pragma unroll
    for (int k = 0; k < KK; ++k) {
        float vv = db[(size_t)ctr_s[k] * SS + tid];
        if (vv < bv) { bv = vv; bk = k; }
    }
    assign[b * SS + tid] = bk;
}

// ---------- cost[b][i] = sum_{j: assign[j]==assign[i]} d[i][j]*wm[j] ----------
// 16 rows per block: wm+assign cached in LDS once, 4 waves x 4 rows,
// barrier-free per-row wave reduction. (R4 measured-good form.)
#define RPB 16
__global__ __launch_bounds__(256) void cost_kernel(const float* __restrict__ d,
                                                   const float* __restrict__ wm,
                                                   const int* __restrict__ assign,
                                                   float* __restrict__ cost) {
    int b = blockIdx.y;
    int tid = threadIdx.x;
    int lane = tid & 63, wv = tid >> 6;
    __shared__ float wmv[SS];
    __shared__ int asg[SS];
    *(float4*)&wmv[tid * 4] = *(const float4*)&wm[b * SS + tid * 4];
    *(int4*)&asg[tid * 4] = *(const int4*)&assign[b * SS + tid * 4];
    __syncthreads();
    const float* db = d + (size_t)b * SS * SS;
#pragma unroll
    for (int r = 0; r < RPB / 4; ++r) {
        int i = blockIdx.x * RPB + wv * (RPB / 4) + r;
        int my = asg[i];
        const float* drow = db + (size_t)i * SS;
        float s = 0.f;
#pragma unroll
        for (int c = 0; c < SS / 256; ++c) {      // 4 sweeps of 64 lanes x float4
            int j = c * 256 + lane * 4;
            float4 dv = *(const float4*)&drow[j];
            float4 wv4 = *(const float4*)&wmv[j];
            int4 a4 = *(const int4*)&asg[j];
            s += (a4.x == my) ? dv.x * wv4.x : 0.f;
            s += (a4.y == my) ? dv.y * wv4.y : 0.f;
            s += (a4.z == my) ? dv.z * wv4.z : 0.f;
            s += (a4.w == my) ? dv.w * wv4.w : 0.f;
        }
#pragma unroll
        for (int off = 32; off; off >>= 1) s += __shfl_down(s, off, 64);
        if (lane == 0) cost[b * SS + i] = s;
    }
}

// ---------- medoid update (+ next assign, or final gather), widened ----------
// grid (4, B): each block redundantly computes all K medoids (cheap 8 KB
// LDS scan), then handles a 256-token quarter of the assign (or gather).
// (R4 measured-good form; 4096 threads/batch for the update phase.)
__global__ __launch_bounds__(1024) void update_assign_kernel(
        const float* __restrict__ d, const float* __restrict__ cost,
        int* __restrict__ assign, const float* __restrict__ x,
        float* __restrict__ out, int last) {
    int b = blockIdx.y;
    int q = blockIdx.x;             // quarter 0..3
    int tid = threadIdx.x;
    int lane = tid & 63, wv = tid >> 6;
    __shared__ float cost_s[SS];
    __shared__ int assign_s[SS];
    __shared__ int ctr_s[KK];
    __shared__ ull pk[4][256];
    cost_s[tid] = cost[b * SS + tid];
    assign_s[tid] = assign[b * SS + tid];
    __syncthreads();
    ull best = ~0ull;
    int k = wv;   // 16 waves, 16 clusters
    for (int c = 0; c < SS / 64; ++c) {
        int i = c * 64 + lane;
        if (assign_s[i] == k) {
            ull key = (((ull)__float_as_uint(cost_s[i])) << 32) | (unsigned)i;
            if (key < best) best = key;
        }
    }
#pragma unroll
    for (int off = 32; off; off >>= 1) {
        ull o = __shfl_down(best, off, 64);
        if (o < best) best = o;
    }
    if (lane == 0) ctr_s[k] = (best == ~0ull) ? 0 : (int)(best & 0xFFFFFFFFu);
    __syncthreads();
    const float* db = d + (size_t)b * SS * SS;
    if (!last) {
        int tok = q * 256 + (tid & 255);
        int g = tid >> 8;
        ull bk = ~0ull;
#pragma unroll
        for (int kk = 0; kk < 4; ++kk) {
            int k2 = g * 4 + kk;
            float vv = db[(size_t)ctr_s[k2] * SS + tok];
            ull key = (((ull)__float_as_uint(vv)) << 32) | (unsigned)k2;
            if (key < bk) bk = key;
        }
        pk[g][tid & 255] = bk;
        __syncthreads();
        if (tid < 256) {
            ull m = pk[0][tid];
            if (pk[1][tid] < m) m = pk[1][tid];
            if (pk[2][tid] < m) m = pk[2][tid];
            if (pk[3][tid] < m) m = pk[3][tid];
            assign[b * SS + q * 256 + tid] = (int)(m & 0xFFFFFFFFu);
        }
    } else {
        int e = q * 1024 + tid;     // FF*KK = 4096 elements total
        int f = e / KK, k2 = e % KK;
        out[((size_t)b * FF + f) * KK + k2] = x[((size_t)b * FF + f) * SS + ctr_s[k2]];
    }
}

extern "C" void kernel_launch(void* const* d_in, const int* in_sizes, int n_in,
                              void* d_out, int out_size, void* d_ws, size_t ws_size,
                              hipStream_t stream) {
    const float* x = (const float*)d_in[0];   // [B,F,S]
    const float* w = (const float*)d_in[1];   // [B,S,S]
    float* out = (float*)d_out;               // [B,F,K]

    char* ws = (char*)d_ws;
    float* d = (float*)ws;                              // B*S*S floats = 33.55 MB
    size_t off = (size_t)BB * SS * SS * sizeof(float);
    float* wm = (float*)(ws + off);   off += (size_t)BB * SS * sizeof(float);
    int* assign = (int*)(ws + off);   off += (size_t)BB * SS * sizeof(int);
    float* cost = (float*)(ws + off); off += (size_t)BB * SS * sizeof(float);
    float* part = (float*)(ws + off); // [ICH][B][S] = 256 KB (non-aliasing:
                                      // consumed by topk AFTER dist runs)

    // dist first, wm_part second — independent; wm_part backfills the tail.
    // 528 triangular 32x32 wave-tiles per batch, 2 waves (2 tiles) per block.
    dist_kernel<<<dim3(264, BB), 128, 0, stream>>>(x, d);
    wm_part_kernel<<<dim3(SS / 256, ICH, BB), 256, 0, stream>>>(w, part);
    topk_assign_kernel<<<BB, 1024, 0, stream>>>(part, wm, d, assign);
    for (int itr = 0; itr < ITERS; ++itr) {
        cost_kernel<<<dim3(SS / RPB, BB), 256, 0, stream>>>(d, wm, assign, cost);
        update_assign_kernel<<<dim3(4, BB), 1024, 0, stream>>>(d, cost, assign, x, out,
                                                               itr == ITERS - 1 ? 1 : 0);
    }
}